// Round 1
// baseline (397.394 us; speedup 1.0000x reference)
//
#include <hip/hip_runtime.h>

#define N_NODES 50000
#define N_EDGES 800000
#define F_IN    128
#define HID     128
#define F_OUT   64
#define BN_EPS  1e-5f

static inline size_t align_up(size_t x, size_t a){ return (x + a - 1) / a * a; }

// ---------------- CSR build ----------------

__global__ void k_hist(const int* __restrict__ dst, int* __restrict__ cnt){
  int e = blockIdx.x * blockDim.x + threadIdx.x;
  if(e < N_EDGES) atomicAdd(&cnt[dst[e]], 1);
}

__global__ void k_scanA(const int* __restrict__ cnt, int* __restrict__ rp, int* __restrict__ part){
  __shared__ int s[256];
  int i = blockIdx.x * 256 + threadIdx.x;
  int v = (i < N_NODES) ? cnt[i] : 0;
  s[threadIdx.x] = v;
  __syncthreads();
  for(int off = 1; off < 256; off <<= 1){
    int t = (threadIdx.x >= off) ? s[threadIdx.x - off] : 0;
    __syncthreads();
    s[threadIdx.x] += t;
    __syncthreads();
  }
  if(i < N_NODES) rp[i] = s[threadIdx.x] - v;      // block-local exclusive
  if(threadIdx.x == 255) part[blockIdx.x] = s[255]; // block total
}

__global__ void k_scanB(int* __restrict__ part, int nb){
  __shared__ int s[256];
  int v = (threadIdx.x < nb) ? part[threadIdx.x] : 0;
  s[threadIdx.x] = v;
  __syncthreads();
  for(int off = 1; off < 256; off <<= 1){
    int t = (threadIdx.x >= off) ? s[threadIdx.x - off] : 0;
    __syncthreads();
    s[threadIdx.x] += t;
    __syncthreads();
  }
  part[threadIdx.x] = s[threadIdx.x] - v;           // exclusive block offsets
}

__global__ void k_scanC(int* __restrict__ rp, const int* __restrict__ part){
  int i = blockIdx.x * 256 + threadIdx.x;
  if(i < N_NODES) rp[i] += part[blockIdx.x];
  if(i == 0) rp[N_NODES] = N_EDGES;
}

__global__ void k_scatter(const int* __restrict__ dst, const int* __restrict__ src,
                          const float* __restrict__ vals, const int* __restrict__ rp,
                          int* __restrict__ cnt, float* __restrict__ ew, int* __restrict__ es){
  int e = blockIdx.x * blockDim.x + threadIdx.x;
  if(e >= N_EDGES) return;
  int d = dst[e];
  int p = rp[d] + atomicAdd(&cnt[d], 1);
  ew[p] = vals[e];
  es[p] = src[e];
}

// ---------------- SpMM 1: agg[i] = sum_e w_e * X[src_e], 128-wide ----------------

__global__ __launch_bounds__(256) void k_spmm1(const float* __restrict__ X,
    const float* __restrict__ ew, const int* __restrict__ es,
    const int* __restrict__ rp, float* __restrict__ agg){
  int w    = (int)((blockIdx.x * blockDim.x + threadIdx.x) >> 6);
  int lane = threadIdx.x & 63;
  if(w >= N_NODES) return;
  int beg = rp[w], end = rp[w + 1];
  float a0 = 0.f, a1 = 0.f;
  int e = beg;
  for(; e + 1 < end; e += 2){
    float wt0 = ew[e];     int s0 = es[e];
    float wt1 = ew[e + 1]; int s1 = es[e + 1];
    float2 v0 = *reinterpret_cast<const float2*>(X + (size_t)s0 * F_IN + lane * 2);
    float2 v1 = *reinterpret_cast<const float2*>(X + (size_t)s1 * F_IN + lane * 2);
    a0 = fmaf(wt0, v0.x, a0); a1 = fmaf(wt0, v0.y, a1);
    a0 = fmaf(wt1, v1.x, a0); a1 = fmaf(wt1, v1.y, a1);
  }
  if(e < end){
    float wt = ew[e]; int s = es[e];
    float2 v = *reinterpret_cast<const float2*>(X + (size_t)s * F_IN + lane * 2);
    a0 = fmaf(wt, v.x, a0); a1 = fmaf(wt, v.y, a1);
  }
  *reinterpret_cast<float2*>(agg + (size_t)w * F_IN + lane * 2) = make_float2(a0, a1);
}

// ---------------- GEMM 1: h_pre = [agg | X] @ W1 + b1, plus BN partial sums ----------------
// 64 nodes x 128 cols per block, 256 threads as 16x16, 4x8 register tile, K chunked by 32.

__global__ __launch_bounds__(256) void k_gemm1(
    const float* __restrict__ agg, const float* __restrict__ X,
    const float* __restrict__ W1, const float* __restrict__ b1,
    float* __restrict__ h_pre, float* __restrict__ bn_acc){
  __shared__ float sS[32][68];    // [k][node], padded
  __shared__ float sW[32][128];   // [k][col]
  const int tid = threadIdx.x;
  const int tx = tid & 15;        // col group (8 cols)
  const int ty = tid >> 4;        // node group (4 nodes)
  const int bn0 = blockIdx.x * 64;

  float acc[4][8];
  #pragma unroll
  for(int i = 0; i < 4; i++)
    #pragma unroll
    for(int j = 0; j < 8; j++) acc[i][j] = 0.f;

  for(int kc = 0; kc < 2 * F_IN; kc += 32){
    const float* src = (kc < F_IN) ? agg : X;
    const int kb = (kc < F_IN) ? kc : (kc - F_IN);
    // stage A: 64 nodes x 32 k (transposed into LDS)
    #pragma unroll
    for(int v = tid; v < 512; v += 256){
      int n = v >> 3, k4 = v & 7;
      int gn = bn0 + n;
      float4 f = make_float4(0.f, 0.f, 0.f, 0.f);
      if(gn < N_NODES)
        f = *reinterpret_cast<const float4*>(src + (size_t)gn * F_IN + kb + k4 * 4);
      sS[k4 * 4 + 0][n] = f.x; sS[k4 * 4 + 1][n] = f.y;
      sS[k4 * 4 + 2][n] = f.z; sS[k4 * 4 + 3][n] = f.w;
    }
    // stage B: 32 k x 128 cols
    #pragma unroll
    for(int v = tid; v < 1024; v += 256){
      int k = v >> 5, c4 = v & 31;
      *reinterpret_cast<float4*>(&sW[k][c4 * 4]) =
        *reinterpret_cast<const float4*>(W1 + (size_t)(kc + k) * HID + c4 * 4);
    }
    __syncthreads();
    #pragma unroll
    for(int k = 0; k < 32; k++){
      float4 a  = *reinterpret_cast<const float4*>(&sS[k][ty * 4]);
      float4 w0 = *reinterpret_cast<const float4*>(&sW[k][tx * 8]);
      float4 w1 = *reinterpret_cast<const float4*>(&sW[k][tx * 8 + 4]);
      float av[4] = {a.x, a.y, a.z, a.w};
      float wv[8] = {w0.x, w0.y, w0.z, w0.w, w1.x, w1.y, w1.z, w1.w};
      #pragma unroll
      for(int i = 0; i < 4; i++)
        #pragma unroll
        for(int j = 0; j < 8; j++)
          acc[i][j] = fmaf(av[i], wv[j], acc[i][j]);
    }
    __syncthreads();
  }

  // epilogue: bias, store h_pre, BN partials
  float psum[8], psq[8];
  #pragma unroll
  for(int j = 0; j < 8; j++){ psum[j] = 0.f; psq[j] = 0.f; }
  #pragma unroll
  for(int i = 0; i < 4; i++){
    int gn = bn0 + ty * 4 + i;
    if(gn < N_NODES){
      float hv[8];
      #pragma unroll
      for(int j = 0; j < 8; j++){
        int c = tx * 8 + j;
        hv[j] = acc[i][j] + b1[c];
        psum[j] += hv[j];
        psq[j]  += hv[j] * hv[j];
      }
      *reinterpret_cast<float4*>(h_pre + (size_t)gn * HID + tx * 8) =
          make_float4(hv[0], hv[1], hv[2], hv[3]);
      *reinterpret_cast<float4*>(h_pre + (size_t)gn * HID + tx * 8 + 4) =
          make_float4(hv[4], hv[5], hv[6], hv[7]);
    }
  }
  // block-level reduction of BN partials (reuse sS: 2176 floats >= 2048)
  __syncthreads();
  float* red = &sS[0][0];
  #pragma unroll
  for(int j = 0; j < 8; j++) red[ty * 128 + tx * 8 + j] = psum[j];
  __syncthreads();
  if(tid < 128){
    float s = 0.f;
    #pragma unroll
    for(int t = 0; t < 16; t++) s += red[t * 128 + tid];
    atomicAdd(&bn_acc[tid], s);
  }
  __syncthreads();
  #pragma unroll
  for(int j = 0; j < 8; j++) red[ty * 128 + tx * 8 + j] = psq[j];
  __syncthreads();
  if(tid < 128){
    float s = 0.f;
    #pragma unroll
    for(int t = 0; t < 16; t++) s += red[t * 128 + tid];
    atomicAdd(&bn_acc[128 + tid], s);
  }
}

// ---------------- BN stats -> scale/shift ----------------

__global__ void k_bnstats(const float* __restrict__ bn_acc, const float* __restrict__ gamma,
                          const float* __restrict__ beta, float* __restrict__ bn_sc){
  int c = threadIdx.x;
  if(c < HID){
    float mean = bn_acc[c] / (float)N_NODES;
    float var  = bn_acc[HID + c] / (float)N_NODES - mean * mean;
    float rs   = rsqrtf(var + BN_EPS);
    float sc   = gamma[c] * rs;
    bn_sc[c]        = sc;
    bn_sc[HID + c]  = beta[c] - mean * sc;
  }
}

// ---------------- GEMM 2: h = relu(bn(h_pre)); y2 = h@W2_top; out = h@W2_bot + b2 ----------------
// B matrix V[k][c]: c<64 -> W2[k][c] (top), c>=64 -> W2[128+k][c-64] (bot). K=128.

__global__ __launch_bounds__(256) void k_gemm2(
    const float* __restrict__ h_pre, const float* __restrict__ W2,
    const float* __restrict__ b2, const float* __restrict__ bn_sc,
    float* __restrict__ y2, float* __restrict__ out){
  __shared__ float sS[32][68];
  __shared__ float sW[32][128];
  __shared__ float s_scale[HID], s_shift[HID];
  const int tid = threadIdx.x;
  if(tid < HID){ s_scale[tid] = bn_sc[tid]; s_shift[tid] = bn_sc[HID + tid]; }
  const int tx = tid & 15;
  const int ty = tid >> 4;
  const int bn0 = blockIdx.x * 64;

  float acc[4][8];
  #pragma unroll
  for(int i = 0; i < 4; i++)
    #pragma unroll
    for(int j = 0; j < 8; j++) acc[i][j] = 0.f;
  __syncthreads();

  for(int kc = 0; kc < HID; kc += 32){
    // stage A with fused BN + ReLU
    #pragma unroll
    for(int v = tid; v < 512; v += 256){
      int n = v >> 3, k4 = v & 7;
      int gn = bn0 + n;
      float4 f = make_float4(0.f, 0.f, 0.f, 0.f);
      if(gn < N_NODES){
        f = *reinterpret_cast<const float4*>(h_pre + (size_t)gn * HID + kc + k4 * 4);
        int k0 = kc + k4 * 4;
        f.x = fmaxf(0.f, fmaf(f.x, s_scale[k0 + 0], s_shift[k0 + 0]));
        f.y = fmaxf(0.f, fmaf(f.y, s_scale[k0 + 1], s_shift[k0 + 1]));
        f.z = fmaxf(0.f, fmaf(f.z, s_scale[k0 + 2], s_shift[k0 + 2]));
        f.w = fmaxf(0.f, fmaf(f.w, s_scale[k0 + 3], s_shift[k0 + 3]));
      }
      sS[k4 * 4 + 0][n] = f.x; sS[k4 * 4 + 1][n] = f.y;
      sS[k4 * 4 + 2][n] = f.z; sS[k4 * 4 + 3][n] = f.w;
    }
    // stage B (V remap of W2)
    #pragma unroll
    for(int v = tid; v < 1024; v += 256){
      int k = v >> 5, c4 = v & 31;
      int gk = kc + k;
      float4 f;
      if(c4 < 16)
        f = *reinterpret_cast<const float4*>(W2 + (size_t)gk * F_OUT + c4 * 4);
      else
        f = *reinterpret_cast<const float4*>(W2 + (size_t)(HID + gk) * F_OUT + (c4 - 16) * 4);
      *reinterpret_cast<float4*>(&sW[k][c4 * 4]) = f;
    }
    __syncthreads();
    #pragma unroll
    for(int k = 0; k < 32; k++){
      float4 a  = *reinterpret_cast<const float4*>(&sS[k][ty * 4]);
      float4 w0 = *reinterpret_cast<const float4*>(&sW[k][tx * 8]);
      float4 w1 = *reinterpret_cast<const float4*>(&sW[k][tx * 8 + 4]);
      float av[4] = {a.x, a.y, a.z, a.w};
      float wv[8] = {w0.x, w0.y, w0.z, w0.w, w1.x, w1.y, w1.z, w1.w};
      #pragma unroll
      for(int i = 0; i < 4; i++)
        #pragma unroll
        for(int j = 0; j < 8; j++)
          acc[i][j] = fmaf(av[i], wv[j], acc[i][j]);
    }
    __syncthreads();
  }

  #pragma unroll
  for(int i = 0; i < 4; i++){
    int gn = bn0 + ty * 4 + i;
    if(gn >= N_NODES) continue;
    if(tx < 8){
      // y2 columns 0..63
      int c0 = tx * 8;
      *reinterpret_cast<float4*>(y2 + (size_t)gn * F_OUT + c0) =
          make_float4(acc[i][0], acc[i][1], acc[i][2], acc[i][3]);
      *reinterpret_cast<float4*>(y2 + (size_t)gn * F_OUT + c0 + 4) =
          make_float4(acc[i][4], acc[i][5], acc[i][6], acc[i][7]);
    } else {
      // direct out part + b2
      int c0 = tx * 8 - 64;
      float hv[8];
      #pragma unroll
      for(int j = 0; j < 8; j++) hv[j] = acc[i][j] + b2[c0 + j];
      *reinterpret_cast<float4*>(out + (size_t)gn * F_OUT + c0) =
          make_float4(hv[0], hv[1], hv[2], hv[3]);
      *reinterpret_cast<float4*>(out + (size_t)gn * F_OUT + c0 + 4) =
          make_float4(hv[4], hv[5], hv[6], hv[7]);
    }
  }
}

// ---------------- SpMM 2: out += A @ y2, 64-wide ----------------

__global__ __launch_bounds__(256) void k_spmm2(const float* __restrict__ y2,
    const float* __restrict__ ew, const int* __restrict__ es,
    const int* __restrict__ rp, float* __restrict__ out){
  int w    = (int)((blockIdx.x * blockDim.x + threadIdx.x) >> 6);
  int lane = threadIdx.x & 63;
  if(w >= N_NODES) return;
  int beg = rp[w], end = rp[w + 1];
  float a = out[(size_t)w * F_OUT + lane];
  int e = beg;
  for(; e + 1 < end; e += 2){
    float wt0 = ew[e];     int s0 = es[e];
    float wt1 = ew[e + 1]; int s1 = es[e + 1];
    float v0 = y2[(size_t)s0 * F_OUT + lane];
    float v1 = y2[(size_t)s1 * F_OUT + lane];
    a = fmaf(wt0, v0, a);
    a = fmaf(wt1, v1, a);
  }
  if(e < end){
    a = fmaf(ew[e], y2[(size_t)es[e] * F_OUT + lane], a);
  }
  out[(size_t)w * F_OUT + lane] = a;
}

// ---------------- launch ----------------

extern "C" void kernel_launch(void* const* d_in, const int* in_sizes, int n_in,
                              void* d_out, int out_size, void* d_ws, size_t ws_size,
                              hipStream_t stream){
  const float* X     = (const float*)d_in[0];
  const float* W1    = (const float*)d_in[1];
  const float* b1    = (const float*)d_in[2];
  const float* gamma = (const float*)d_in[3];
  const float* beta  = (const float*)d_in[4];
  const float* W2    = (const float*)d_in[5];
  const float* b2    = (const float*)d_in[6];
  const float* evals = (const float*)d_in[7];
  const int*   esrc  = (const int*)d_in[8];
  const int*   edst  = (const int*)d_in[9];
  float* out = (float*)d_out;

  char* ws = (char*)d_ws;
  size_t off = 0;
  auto carve = [&](size_t bytes) -> char* {
    off = align_up(off, 256);
    char* p = ws + off;
    off += bytes;
    return p;
  };
  int*   cnt    = (int*)  carve((size_t)N_NODES * 4);
  int*   rp     = (int*)  carve(((size_t)N_NODES + 1) * 4);
  int*   part   = (int*)  carve(256 * 4);
  float* bn_acc = (float*)carve(256 * 4);
  float* bn_sc  = (float*)carve(256 * 4);
  float* ew     = (float*)carve((size_t)N_EDGES * 4);
  int*   es     = (int*)  carve((size_t)N_EDGES * 4);
  float* agg    = (float*)carve((size_t)N_NODES * F_IN * 4);
  float* hpre   = (float*)carve((size_t)N_NODES * HID * 4);
  float* y2     = (float*)carve((size_t)N_NODES * F_OUT * 4);

  hipMemsetAsync(cnt, 0, (size_t)N_NODES * 4, stream);
  hipMemsetAsync(bn_acc, 0, 256 * 4, stream);

  const int SCAN_BLOCKS = (N_NODES + 255) / 256;  // 196

  k_hist<<<(N_EDGES + 255) / 256, 256, 0, stream>>>(edst, cnt);
  k_scanA<<<SCAN_BLOCKS, 256, 0, stream>>>(cnt, rp, part);
  k_scanB<<<1, 256, 0, stream>>>(part, SCAN_BLOCKS);
  k_scanC<<<SCAN_BLOCKS, 256, 0, stream>>>(rp, part);
  hipMemsetAsync(cnt, 0, (size_t)N_NODES * 4, stream);
  k_scatter<<<(N_EDGES + 255) / 256, 256, 0, stream>>>(edst, esrc, evals, rp, cnt, ew, es);

  k_spmm1<<<N_NODES / 4, 256, 0, stream>>>(X, ew, es, rp, agg);
  k_gemm1<<<(N_NODES + 63) / 64, 256, 0, stream>>>(agg, X, W1, b1, hpre, bn_acc);
  k_bnstats<<<1, 128, 0, stream>>>(bn_acc, gamma, beta, bn_sc);
  k_gemm2<<<(N_NODES + 63) / 64, 256, 0, stream>>>(hpre, W2, b2, bn_sc, y2, out);
  k_spmm2<<<N_NODES / 4, 256, 0, stream>>>(y2, ew, es, rp, out);
}

// Round 2
// 352.115 us; speedup vs baseline: 1.1286x; 1.1286x over previous
//
#include <hip/hip_runtime.h>

#define N_NODES 50000
#define N_EDGES 800000
#define F_IN    128
#define HID     128
#define F_OUT   64
#define BN_EPS  1e-5f

typedef __bf16 bf16x8 __attribute__((ext_vector_type(8)));
typedef float  f32x4  __attribute__((ext_vector_type(4)));

static inline size_t align_up(size_t x, size_t a){ return (x + a - 1) / a * a; }

__device__ __forceinline__ float bflo(unsigned u){ return __uint_as_float(u << 16); }
__device__ __forceinline__ float bfhi(unsigned u){ return __uint_as_float(u & 0xffff0000u); }
__device__ __forceinline__ unsigned packbf(float a, float b){
  __bf16 ha = (__bf16)a, hb = (__bf16)b;
  unsigned short ua = __builtin_bit_cast(unsigned short, ha);
  unsigned short ub = __builtin_bit_cast(unsigned short, hb);
  return (unsigned)ua | ((unsigned)ub << 16);
}

// ---------------- CSR build ----------------

__global__ void k_hist(const int* __restrict__ dst, int* __restrict__ cnt){
  int e = blockIdx.x * blockDim.x + threadIdx.x;
  if(e < N_EDGES) atomicAdd(&cnt[dst[e]], 1);
}

__global__ void k_scanA(const int* __restrict__ cnt, int* __restrict__ rp, int* __restrict__ part){
  __shared__ int s[256];
  int i = blockIdx.x * 256 + threadIdx.x;
  int v = (i < N_NODES) ? cnt[i] : 0;
  s[threadIdx.x] = v;
  __syncthreads();
  for(int off = 1; off < 256; off <<= 1){
    int t = (threadIdx.x >= off) ? s[threadIdx.x - off] : 0;
    __syncthreads();
    s[threadIdx.x] += t;
    __syncthreads();
  }
  if(i < N_NODES) rp[i] = s[threadIdx.x] - v;
  if(threadIdx.x == 255) part[blockIdx.x] = s[255];
}

__global__ void k_scanB(int* __restrict__ part, int nb){
  __shared__ int s[256];
  int v = (threadIdx.x < nb) ? part[threadIdx.x] : 0;
  s[threadIdx.x] = v;
  __syncthreads();
  for(int off = 1; off < 256; off <<= 1){
    int t = (threadIdx.x >= off) ? s[threadIdx.x - off] : 0;
    __syncthreads();
    s[threadIdx.x] += t;
    __syncthreads();
  }
  part[threadIdx.x] = s[threadIdx.x] - v;
}

__global__ void k_scanC(int* __restrict__ rp, const int* __restrict__ part){
  int i = blockIdx.x * 256 + threadIdx.x;
  if(i < N_NODES) rp[i] += part[blockIdx.x];
  if(i == 0) rp[N_NODES] = N_EDGES;
}

__global__ void k_scatter(const int* __restrict__ dst, const int* __restrict__ src,
                          const float* __restrict__ vals, const int* __restrict__ rp,
                          int* __restrict__ cnt, float* __restrict__ ew, int* __restrict__ es){
  int e = blockIdx.x * blockDim.x + threadIdx.x;
  if(e >= N_EDGES) return;
  int d = dst[e];
  int p = rp[d] + atomicAdd(&cnt[d], 1);
  ew[p] = vals[e];
  es[p] = src[e];
}

// ---------------- weight prep: frag-ordered bf16 tables ----------------
// b_frag convention: lane l holds B[k = ks*32 + (l>>4)*8 + i][c = nf*16 + (l&15)]
// W1f slot index: (ks*8 + nf)*64 + l  (ks 0..7, nf 0..7) -> 8 bf16 each
// W2f: V[k][c] = c<64 ? W2[k][c] : W2[128+k][c-64]; ks 0..3, nf 0..7

__global__ void k_prepW(const float* __restrict__ W1, const float* __restrict__ W2,
                        __bf16* __restrict__ W1f, __bf16* __restrict__ W2f){
  int t = blockIdx.x * 256 + threadIdx.x;
  if(t < 4096){
    int ks = t >> 9, rem = t & 511, nf = rem >> 6, l = rem & 63;
    int k = ks * 32 + (l >> 4) * 8, c = nf * 16 + (l & 15);
    bf16x8 v;
    #pragma unroll
    for(int i = 0; i < 8; i++) v[i] = (__bf16)W1[(size_t)(k + i) * HID + c];
    *(bf16x8*)(W1f + ((size_t)t << 3)) = v;
  } else if(t < 6144){
    int s = t - 4096;
    int ks = s >> 9, rem = s & 511, nf = rem >> 6, l = rem & 63;
    int k = ks * 32 + (l >> 4) * 8, c = nf * 16 + (l & 15);
    bf16x8 v;
    #pragma unroll
    for(int i = 0; i < 8; i++){
      int kk = k + i;
      float val = (c < 64) ? W2[(size_t)kk * F_OUT + c]
                           : W2[(size_t)(HID + kk) * F_OUT + (c - 64)];
      v[i] = (__bf16)val;
    }
    *(bf16x8*)(W2f + ((size_t)s << 3)) = v;
  }
}

// ---------------- X -> bf16 into S cols 128..255 ----------------
// S is [N][256] bf16: cols 0..127 = agg (written by spmm1), 128..255 = X

__global__ __launch_bounds__(256) void k_cvtX(const float* __restrict__ X, __bf16* __restrict__ S){
  int t = blockIdx.x * 256 + threadIdx.x;      // 800000 threads, 8 elems each
  if(t >= N_NODES * 16) return;
  int n = t >> 4;
  int c = (t & 15) * 8;
  const float* xp = X + (size_t)n * F_IN + c;
  f32x4 x0 = *(const f32x4*)xp;
  f32x4 x1 = *(const f32x4*)(xp + 4);
  bf16x8 v;
  #pragma unroll
  for(int i = 0; i < 4; i++){ v[i] = (__bf16)x0[i]; v[4 + i] = (__bf16)x1[i]; }
  *(bf16x8*)(S + (size_t)n * 256 + 128 + c) = v;
}

// ---------------- SpMM 1: S[w][0..127] = sum_e w_e * Xb[src_e]  (bf16 in, bf16 out) ----------------

__global__ __launch_bounds__(256) void k_spmm1(__bf16* __restrict__ S,
    const float* __restrict__ ew, const int* __restrict__ es, const int* __restrict__ rp){
  int w    = (int)((blockIdx.x * blockDim.x + threadIdx.x) >> 6);
  int lane = threadIdx.x & 63;
  if(w >= N_NODES) return;
  int beg = rp[w], end = rp[w + 1];
  const __bf16* Xb = S + 128;
  float a0 = 0.f, a1 = 0.f;
  int e = beg;
  for(; e + 1 < end; e += 2){
    float w0 = ew[e];     int s0 = es[e];
    float w1 = ew[e + 1]; int s1 = es[e + 1];
    unsigned u0 = *(const unsigned*)(Xb + (size_t)s0 * 256 + lane * 2);
    unsigned u1 = *(const unsigned*)(Xb + (size_t)s1 * 256 + lane * 2);
    a0 = fmaf(w0, bflo(u0), a0); a1 = fmaf(w0, bfhi(u0), a1);
    a0 = fmaf(w1, bflo(u1), a0); a1 = fmaf(w1, bfhi(u1), a1);
  }
  if(e < end){
    float wt = ew[e]; int s = es[e];
    unsigned u = *(const unsigned*)(Xb + (size_t)s * 256 + lane * 2);
    a0 = fmaf(wt, bflo(u), a0); a1 = fmaf(wt, bfhi(u), a1);
  }
  *(unsigned*)(S + (size_t)w * 256 + lane * 2) = packbf(a0, a1);
}

// ---------------- GEMM 1 (MFMA): h_pre = S @ W1 + b1, + BN partials ----------------
// Block: 64 rows x 128 cols, 4 waves (wm 0..1 x wn 0..1), wave = 32 rows x 64 cols.
// K = 256 (cols of S), 8 ksteps of 32. No LDS staging; A/B frags direct from global.

__global__ __launch_bounds__(256) void k_gemm1(
    const __bf16* __restrict__ S, const __bf16* __restrict__ W1f,
    const float* __restrict__ b1, float* __restrict__ hpre, float* __restrict__ bn_acc){
  __shared__ float bnred[2][256];
  const int tid = threadIdx.x;
  const int lane = tid & 63, wid = tid >> 6;
  const int wm = wid >> 1, wn = wid & 1;
  const int lr = lane & 15, lk = (lane >> 4) * 8;
  const int rbase = blockIdx.x * 64 + wm * 32 + lr;

  f32x4 acc[2][4];
  #pragma unroll
  for(int m = 0; m < 2; m++)
    #pragma unroll
    for(int n = 0; n < 4; n++) acc[m][n] = (f32x4){0.f, 0.f, 0.f, 0.f};

  for(int ks = 0; ks < 8; ks++){
    bf16x8 a[2], b[4];
    #pragma unroll
    for(int m = 0; m < 2; m++){
      int r = rbase + m * 16; if(r > N_NODES - 1) r = N_NODES - 1;
      a[m] = *(const bf16x8*)(S + (size_t)r * 256 + ks * 32 + lk);
    }
    #pragma unroll
    for(int n = 0; n < 4; n++)
      b[n] = *(const bf16x8*)(W1f + (((ks * 8 + wn * 4 + n) * 64 + lane) << 3));
    #pragma unroll
    for(int m = 0; m < 2; m++)
      #pragma unroll
      for(int n = 0; n < 4; n++)
        acc[m][n] = __builtin_amdgcn_mfma_f32_16x16x32_bf16(a[m], b[n], acc[m][n], 0, 0, 0);
  }

  #pragma unroll
  for(int n = 0; n < 4; n++){
    int gc = wn * 64 + n * 16 + lr;
    float bias = b1[gc];
    float ps = 0.f, pq = 0.f;
    #pragma unroll
    for(int m = 0; m < 2; m++){
      int gr0 = blockIdx.x * 64 + wm * 32 + m * 16 + (lane >> 4) * 4;
      #pragma unroll
      for(int i = 0; i < 4; i++){
        int r = gr0 + i;
        if(r < N_NODES){
          float h = acc[m][n][i] + bias;
          hpre[(size_t)r * HID + gc] = h;
          ps += h; pq += h * h;
        }
      }
    }
    ps += __shfl_xor(ps, 16); ps += __shfl_xor(ps, 32);
    pq += __shfl_xor(pq, 16); pq += __shfl_xor(pq, 32);
    if(lane < 16){
      bnred[wm][gc] = ps;
      bnred[wm][128 + gc] = pq;
    }
  }
  __syncthreads();
  atomicAdd(&bn_acc[tid], bnred[0][tid] + bnred[1][tid]);
}

// ---------------- BN stats -> scale/shift ----------------

__global__ void k_bnstats(const float* __restrict__ bn_acc, const float* __restrict__ gamma,
                          const float* __restrict__ beta, float* __restrict__ bn_sc){
  int c = threadIdx.x;
  if(c < HID){
    float mean = bn_acc[c] / (float)N_NODES;
    float var  = bn_acc[HID + c] / (float)N_NODES - mean * mean;
    float rs   = rsqrtf(var + BN_EPS);
    float sc   = gamma[c] * rs;
    bn_sc[c]       = sc;
    bn_sc[HID + c] = beta[c] - mean * sc;
  }
}

// ---------------- GEMM 2 (MFMA): h = relu(bn(h_pre)) fused into A-frags ----------------
// cols 0..63 (wn=0) -> y2 = h@W2_top (bf16); cols 64..127 (wn=1) -> out = h@W2_bot + b2 (f32)

__global__ __launch_bounds__(256) void k_gemm2(
    const float* __restrict__ hpre, const __bf16* __restrict__ W2f,
    const float* __restrict__ b2, const float* __restrict__ bn_sc,
    __bf16* __restrict__ y2b, float* __restrict__ out){
  const int tid = threadIdx.x;
  const int lane = tid & 63, wid = tid >> 6;
  const int wm = wid >> 1, wn = wid & 1;
  const int lr = lane & 15, lk = (lane >> 4) * 8;
  const int rbase = blockIdx.x * 64 + wm * 32 + lr;

  f32x4 acc[2][4];
  #pragma unroll
  for(int m = 0; m < 2; m++)
    #pragma unroll
    for(int n = 0; n < 4; n++) acc[m][n] = (f32x4){0.f, 0.f, 0.f, 0.f};

  for(int ks = 0; ks < 4; ks++){
    int k0 = ks * 32 + lk;
    f32x4 sc0 = *(const f32x4*)(bn_sc + k0);
    f32x4 sc1 = *(const f32x4*)(bn_sc + k0 + 4);
    f32x4 sh0 = *(const f32x4*)(bn_sc + 128 + k0);
    f32x4 sh1 = *(const f32x4*)(bn_sc + 128 + k0 + 4);
    bf16x8 a[2], b[4];
    #pragma unroll
    for(int m = 0; m < 2; m++){
      int r = rbase + m * 16; if(r > N_NODES - 1) r = N_NODES - 1;
      const float* hp = hpre + (size_t)r * HID + k0;
      f32x4 h0 = *(const f32x4*)hp;
      f32x4 h1 = *(const f32x4*)(hp + 4);
      bf16x8 af;
      #pragma unroll
      for(int i = 0; i < 4; i++){
        af[i]     = (__bf16)fmaxf(0.f, fmaf(h0[i], sc0[i], sh0[i]));
        af[4 + i] = (__bf16)fmaxf(0.f, fmaf(h1[i], sc1[i], sh1[i]));
      }
      a[m] = af;
    }
    #pragma unroll
    for(int n = 0; n < 4; n++)
      b[n] = *(const bf16x8*)(W2f + (((ks * 8 + wn * 4 + n) * 64 + lane) << 3));
    #pragma unroll
    for(int m = 0; m < 2; m++)
      #pragma unroll
      for(int n = 0; n < 4; n++)
        acc[m][n] = __builtin_amdgcn_mfma_f32_16x16x32_bf16(a[m], b[n], acc[m][n], 0, 0, 0);
  }

  #pragma unroll
  for(int n = 0; n < 4; n++){
    int c = n * 16 + lr;                       // 0..63 within half
    float bias = (wn == 1) ? b2[c] : 0.f;
    #pragma unroll
    for(int m = 0; m < 2; m++){
      int gr0 = blockIdx.x * 64 + wm * 32 + m * 16 + (lane >> 4) * 4;
      #pragma unroll
      for(int i = 0; i < 4; i++){
        int r = gr0 + i;
        if(r < N_NODES){
          if(wn == 0) y2b[(size_t)r * F_OUT + c] = (__bf16)acc[m][n][i];
          else        out[(size_t)r * F_OUT + c] = acc[m][n][i] + bias;
        }
      }
    }
  }
}

// ---------------- SpMM 2: out += A @ y2 (bf16 gather, 2 edges per wave-iter) ----------------

__global__ __launch_bounds__(256) void k_spmm2(const __bf16* __restrict__ y2b,
    const float* __restrict__ ew, const int* __restrict__ es,
    const int* __restrict__ rp, float* __restrict__ out){
  int w    = (int)((blockIdx.x * blockDim.x + threadIdx.x) >> 6);
  int lane = threadIdx.x & 63;
  if(w >= N_NODES) return;
  int beg = rp[w], end = rp[w + 1];
  int half = lane >> 5, li = lane & 31;
  float a0 = 0.f, a1 = 0.f;
  for(int e = beg + half; e < end; e += 2){
    float wt = ew[e]; int s = es[e];
    unsigned u = *(const unsigned*)(y2b + (size_t)s * F_OUT + li * 2);
    a0 = fmaf(wt, bflo(u), a0);
    a1 = fmaf(wt, bfhi(u), a1);
  }
  a0 += __shfl_xor(a0, 32);
  a1 += __shfl_xor(a1, 32);
  if(lane < 32){
    float2 o = *(float2*)(out + (size_t)w * F_OUT + li * 2);
    o.x += a0; o.y += a1;
    *(float2*)(out + (size_t)w * F_OUT + li * 2) = o;
  }
}

// ---------------- launch ----------------

extern "C" void kernel_launch(void* const* d_in, const int* in_sizes, int n_in,
                              void* d_out, int out_size, void* d_ws, size_t ws_size,
                              hipStream_t stream){
  const float* X     = (const float*)d_in[0];
  const float* W1    = (const float*)d_in[1];
  const float* b1    = (const float*)d_in[2];
  const float* gamma = (const float*)d_in[3];
  const float* beta  = (const float*)d_in[4];
  const float* W2    = (const float*)d_in[5];
  const float* b2    = (const float*)d_in[6];
  const float* evals = (const float*)d_in[7];
  const int*   esrc  = (const int*)d_in[8];
  const int*   edst  = (const int*)d_in[9];
  float* out = (float*)d_out;

  char* ws = (char*)d_ws;
  size_t off = 0;
  auto carve = [&](size_t bytes) -> char* {
    off = align_up(off, 256);
    char* p = ws + off;
    off += bytes;
    return p;
  };
  int*     cnt    = (int*)    carve((size_t)N_NODES * 4);
  int*     rp     = (int*)    carve(((size_t)N_NODES + 1) * 4);
  int*     part   = (int*)    carve(256 * 4);
  float*   bn_acc = (float*)  carve(256 * 4);
  float*   bn_sc  = (float*)  carve(256 * 4);
  float*   ew     = (float*)  carve((size_t)N_EDGES * 4);
  int*     es     = (int*)    carve((size_t)N_EDGES * 4);
  __bf16*  W1f    = (__bf16*) carve((size_t)4096 * 8 * 2);
  __bf16*  W2f    = (__bf16*) carve((size_t)2048 * 8 * 2);
  __bf16*  S      = (__bf16*) carve((size_t)N_NODES * 256 * 2);
  float*   hpre   = (float*)  carve((size_t)N_NODES * HID * 4);
  __bf16*  y2b    = (__bf16*) carve((size_t)N_NODES * F_OUT * 2);

  hipMemsetAsync(cnt, 0, (size_t)N_NODES * 4, stream);
  hipMemsetAsync(bn_acc, 0, 256 * 4, stream);

  const int SCAN_BLOCKS = (N_NODES + 255) / 256;  // 196

  k_hist<<<(N_EDGES + 255) / 256, 256, 0, stream>>>(edst, cnt);
  k_scanA<<<SCAN_BLOCKS, 256, 0, stream>>>(cnt, rp, part);
  k_scanB<<<1, 256, 0, stream>>>(part, SCAN_BLOCKS);
  k_scanC<<<SCAN_BLOCKS, 256, 0, stream>>>(rp, part);
  hipMemsetAsync(cnt, 0, (size_t)N_NODES * 4, stream);
  k_scatter<<<(N_EDGES + 255) / 256, 256, 0, stream>>>(edst, esrc, evals, rp, cnt, ew, es);

  k_prepW<<<24, 256, 0, stream>>>(W1, W2, W1f, W2f);
  k_cvtX<<<(N_NODES * 16 + 255) / 256, 256, 0, stream>>>(X, S);

  k_spmm1<<<N_NODES / 4, 256, 0, stream>>>(S, ew, es, rp);
  k_gemm1<<<(N_NODES + 63) / 64, 256, 0, stream>>>(S, W1f, b1, hpre, bn_acc);
  k_bnstats<<<1, 128, 0, stream>>>(bn_acc, gamma, beta, bn_sc);
  k_gemm2<<<(N_NODES + 63) / 64, 256, 0, stream>>>(hpre, W2f, b2, bn_sc, y2b, out);
  k_spmm2<<<N_NODES / 4, 256, 0, stream>>>(y2b, ew, es, rp, out);
}